// Round 15
// baseline (163.693 us; speedup 1.0000x reference)
//
#include <hip/hip_runtime.h>
#include <stdint.h>

// ---------------------------------------------------------------------------
// cha_third_conv: polynomial channel expansion (L=8, orders 1..3) + 1x1 conv.
// GEMM view: M=B*H*W=12544, N=256, K=32 groups * 164 feats (padded to 192).
// Round 15: on the r14 base (dbuf ldsA, 1 barrier/group, B-prefetch, M64xN128,
// 4 waves — steady 80us, grid-limited at 1.5 blocks/CU):
//   1) split-K x2 TWO-PASS (plain stores, no atomics — r12 proved split-K
//      math passes; atomics' 8x write-amp was the cost): grid (196,2,2)=784
//      blocks (~3/CU); z=0 -> out (+bias), z=1 -> workspace partial;
//      reduce_add kernel does out += part (float4). ws_size-guarded with
//      fallback to nz=1 (= exact r14 behavior).
//   2) prep_w rewritten: 1 thread = 8 outputs (one 16B coalesced write),
//      768 blocks, no LDS/barrier; kmap reads wave-uniform (scalar).
// Feature math / weight mapping / MFMA core: bit-identical to r9/r14.
// ---------------------------------------------------------------------------

typedef short bf16x8 __attribute__((ext_vector_type(8)));
typedef float f32x4  __attribute__((ext_vector_type(4)));

__device__ __forceinline__ unsigned f2bf(float f) {
  unsigned u = __float_as_uint(f);
  return ((u + 0x7FFFu + ((u >> 16) & 1u)) >> 16) & 0xFFFFu;   // RTNE
}
__device__ __forceinline__ unsigned pk2(float lo, float hi) {
  return f2bf(lo) | (f2bf(hi) << 16);                          // r9 proven
}

#define ROW_S 200   // A-tile row stride in shorts (400 B) — r9 layout

// ---------------------------------------------------------------------------
// CANONICAL enumeration (r9 proven): pairs (a<=b) lex, triples (a<=b<=c) lex.
// ---------------------------------------------------------------------------
constexpr int PI(int b, int c) { return 8 * b - b * (b - 1) / 2 + (c - b); }

struct CTab {
  unsigned char pa[36], pb[36];             // pair slot q -> (a,b), a<=b
  unsigned char ta[120], tb[120], tc3[120]; // triple slot r -> (a,b,c) sorted
};
constexpr CTab gen_ctab() {
  CTab t{};
  int n = 0;
  for (int a = 0; a < 8; ++a)
    for (int b = a; b < 8; ++b) { t.pa[n] = (unsigned char)a; t.pb[n] = (unsigned char)b; ++n; }
  int m = 0;
  for (int a = 0; a < 8; ++a)
    for (int b = a; b < 8; ++b)
      for (int c = b; c < 8; ++c) {
        t.ta[m] = (unsigned char)a; t.tb[m] = (unsigned char)b; t.tc3[m] = (unsigned char)c; ++m;
      }
  return t;
}
constexpr CTab CT = gen_ctab();
__device__ const CTab dCT = CT;   // memory copy for build_kmap

// feature K (canonical slot) from register x[8] and pair products pr[36]
template <int K>
__device__ __forceinline__ float featc(const float* __restrict__ x,
                                       const float* __restrict__ pr) {
  if constexpr (K < 8) {
    return x[K];
  } else if constexpr (K < 44) {
    return pr[K - 8];
  } else if constexpr (K < 164) {
    constexpr int r = K - 44;
    constexpr int a = CT.ta[r], b = CT.tb[r], c = CT.tc3[r];
    return x[a] * pr[PI(b, c)];            // pair product rounds first (as ref)
  } else {
    return 0.0f;                           // pad slots 164..167
  }
}

// one 16B chunk = canonical slots 8*CH .. 8*CH+7 at linear chunk position CH
template <int CH>
__device__ __forceinline__ void emit_chunk(const float* __restrict__ x,
                                           const float* __restrict__ pr,
                                           short* __restrict__ arow) {
  unsigned u0 = pk2(featc<CH * 8 + 0>(x, pr), featc<CH * 8 + 1>(x, pr));
  unsigned u1 = pk2(featc<CH * 8 + 2>(x, pr), featc<CH * 8 + 3>(x, pr));
  unsigned u2 = pk2(featc<CH * 8 + 4>(x, pr), featc<CH * 8 + 5>(x, pr));
  unsigned u3 = pk2(featc<CH * 8 + 6>(x, pr), featc<CH * 8 + 7>(x, pr));
  uint4 v; v.x = u0; v.y = u1; v.z = u2; v.w = u3;
  *reinterpret_cast<uint4*>(arow + (CH << 3)) = v;   // 16B aligned
}

// 4-way part split (part = wave): chunk ranges 0-5 / 6-10 / 11-15 / 16-20
__device__ __forceinline__ void stage_q0(const float* x, const float* pr, short* arow) {
  emit_chunk<0>(x, pr, arow);  emit_chunk<1>(x, pr, arow);  emit_chunk<2>(x, pr, arow);
  emit_chunk<3>(x, pr, arow);  emit_chunk<4>(x, pr, arow);  emit_chunk<5>(x, pr, arow);
}
__device__ __forceinline__ void stage_q1(const float* x, const float* pr, short* arow) {
  emit_chunk<6>(x, pr, arow);  emit_chunk<7>(x, pr, arow);  emit_chunk<8>(x, pr, arow);
  emit_chunk<9>(x, pr, arow);  emit_chunk<10>(x, pr, arow);
}
__device__ __forceinline__ void stage_q2(const float* x, const float* pr, short* arow) {
  emit_chunk<11>(x, pr, arow); emit_chunk<12>(x, pr, arow); emit_chunk<13>(x, pr, arow);
  emit_chunk<14>(x, pr, arow); emit_chunk<15>(x, pr, arow);
}
__device__ __forceinline__ void stage_q3(const float* x, const float* pr, short* arow) {
  emit_chunk<16>(x, pr, arow); emit_chunk<17>(x, pr, arow); emit_chunk<18>(x, pr, arow);
  emit_chunk<19>(x, pr, arow); emit_chunk<20>(x, pr, arow);
}

__device__ __forceinline__ void stage_dispatch(int part, const float* x,
                                               short* arow) {
  float pr[36];
#pragma unroll
  for (int a = 0; a < 8; ++a)
#pragma unroll
    for (int b = a; b < 8; ++b) pr[PI(a, b)] = x[a] * x[b];
  if      (part == 0) stage_q0(x, pr, arow);
  else if (part == 1) stage_q1(x, pr, arow);
  else if (part == 2) stage_q2(x, pr, arow);
  else                stage_q3(x, pr, arow);
}

// ---------------------------------------------------------------------------
// build_kmap — ONE block; r9's exact signature search, result to workspace.
// ---------------------------------------------------------------------------
__global__ void build_kmap(const int* __restrict__ pm2, const int* __restrict__ pcm,
                           int* __restrict__ kmapG) {
  __shared__ unsigned short rsig[164];
  const int tid = threadIdx.x;

  if (tid < 164) {       // reference-order signatures from RUNTIME tables
    unsigned s;
    if (tid < 8) {
      s = 1u << (2 * tid);
    } else if (tid < 44) {
      int q = tid - 8;
      s = (1u << (2 * pm2[2 * q])) + (1u << (2 * pm2[2 * q + 1]));
    } else {
      int r = tid - 44;
      int c0 = pcm[2 * r], pos = pcm[2 * r + 1];
      s = (1u << (2 * c0)) + (1u << (2 * pm2[2 * pos])) + (1u << (2 * pm2[2 * pos + 1]));
    }
    rsig[tid] = (unsigned short)s;
  }
  __syncthreads();

  if (tid < 192) {       // canonical slot -> reference position
    int kk = -1;
    if (tid < 164) {
      unsigned cs;
      if (tid < 8) {
        cs = 1u << (2 * tid);
      } else if (tid < 44) {
        int q = tid - 8;
        cs = (1u << (2 * dCT.pa[q])) + (1u << (2 * dCT.pb[q]));
      } else {
        int r = tid - 44;
        cs = (1u << (2 * dCT.ta[r])) + (1u << (2 * dCT.tb[r])) + (1u << (2 * dCT.tc3[r]));
      }
      for (int t = 0; t < 164; ++t)
        if (rsig[t] == (unsigned short)cs) { kk = t; break; }
    }
    kmapG[tid] = kk;
  }
}

// ---------------------------------------------------------------------------
// prep_w — 1 thread = 8 outputs (one 16B write, fully coalesced), no LDS.
// t = (sg*4+q)*256 + n; reads w[n*5248 + g*164 + kmap[s*32+q*8+j]], j=0..7.
// kmap indices are wave-uniform (t2 shared across the block) -> scalar loads.
// ---------------------------------------------------------------------------
__global__ __launch_bounds__(256) void prep_w(const float* __restrict__ w,
                                              const int* __restrict__ kmapG,
                                              short* __restrict__ wout) {
  int t  = blockIdx.x * 256 + threadIdx.x;   // < 196,608
  int n  = t & 255;
  int t2 = t >> 8;                           // sg*4+q (block-uniform)
  int q  = t2 & 3;
  int sg = t2 >> 2;                          // 0..191
  int g  = sg / 6;
  int s  = sg - g * 6;
  const float* wrow = w + (size_t)n * 5248u + g * 164;
  unsigned v[8];
#pragma unroll
  for (int j = 0; j < 8; ++j) {
    int kk = kmapG[s * 32 + q * 8 + j];      // uniform -> s_load
    v[j] = (kk >= 0) ? f2bf(wrow[kk]) : 0u;
  }
  uint4 o;
  o.x = v[0] | (v[1] << 16);
  o.y = v[2] | (v[3] << 16);
  o.z = v[4] | (v[5] << 16);
  o.w = v[6] | (v[7] << 16);
  *reinterpret_cast<uint4*>(wout + ((size_t)t << 3)) = o;
}

// ---------------------------------------------------------------------------
// Main fused kernel — r14 core. Grid: (196 M-tiles of 64) x (2 N-tiles of
// 128) x nz. Block: 256 threads = 4 waves; wave = N-quarter AND stage part.
// blockIdx.z selects K-range [z*kcount, +kcount); z=0 -> out (+bias),
// z>0 -> part (plain stores; reduce_add combines).
// ---------------------------------------------------------------------------
__global__ __launch_bounds__(256, 3) void poly_gemm(
    const float* __restrict__ in, const short* __restrict__ wbf,
    const float* __restrict__ bias, float* __restrict__ out,
    float* __restrict__ part, int kcount) {
  __shared__ __align__(16) short ldsA[2][64 * ROW_S];   // 51,200 B

  const int tid   = threadIdx.x;
  const int m0    = blockIdx.x * 64;
  const int n0    = blockIdx.y * 128;
  const int khalf = blockIdx.z;
  const int kbase = khalf * kcount;
  const int lane  = tid & 63;       // pixel within tile
  const int wave  = tid >> 6;       // 0..3: wn AND stage part
  const int quad  = lane >> 4;
  const int l16   = lane & 15;
  float* dst = khalf ? part : out;

  // zero k-pad shorts 168..199 of both buffers (4 x uint4 per row)
  {
    uint4 z; z.x = 0u; z.y = 0u; z.z = 0u; z.w = 0u;
    for (int i = tid; i < 2 * 64 * 4; i += 256) {
      int b   = i >> 8;
      int rem = i & 255;
      int row = rem >> 2;
      int q4  = rem & 3;
      *reinterpret_cast<uint4*>(&ldsA[b][row * ROW_S + 168 + q4 * 8]) = z;
    }
  }

  f32x4 acc[4][2];
#pragma unroll
  for (int mf = 0; mf < 4; mf++)
#pragma unroll
    for (int nf = 0; nf < 2; nf++) acc[mf][nf] = (f32x4){0.f, 0.f, 0.f, 0.f};

  const unsigned bb = (unsigned)m0 / 3136u;     // tile fits one image (3136=49*64)
  const unsigned pp = (unsigned)m0 - bb * 3136u;
  const float* xbase = in + (size_t)bb * 802816u + pp + lane
                          + (size_t)(kbase * 8) * 3136u;

  // prologue: x(kbase) -> stage ldsA[0]; then x(kbase+1) -> xr; one barrier
  float xr[8];
#pragma unroll
  for (int c = 0; c < 8; ++c) xr[c] = xbase[(size_t)c * 3136u];
  stage_dispatch(wave, xr, &ldsA[0][lane * ROW_S]);
#pragma unroll
  for (int c = 0; c < 8; ++c) xr[c] = xbase[(size_t)(8 + c) * 3136u];
  __syncthreads();

  int cur = 0;
  for (int gi = 0; gi < kcount; ++gi) {
    const int g = kbase + gi;
    // (1) issue: B fragments of group g into registers
    bf16x8 ball[6][2];
#pragma unroll
    for (int ks = 0; ks < 6; ++ks) {
      const int sg = g * 6 + ks;
#pragma unroll
      for (int nf = 0; nf < 2; ++nf) {
        int n = n0 + wave * 32 + nf * 16 + l16;
        ball[ks][nf] = *(const bf16x8*)(wbf + (((size_t)(sg * 4 + quad) * 256 + n) << 3));
      }
    }
    // (1b) issue: x(gi+2) loads
    float xn[8];
    if (gi + 2 < kcount) {
      const float* xp = xbase + (size_t)((gi + 2) * 8) * 3136u;
#pragma unroll
      for (int c = 0; c < 8; ++c) xn[c] = xp[(size_t)c * 3136u];
    }

    // (2) stage(gi+1) from xr into the other buffer — VALU covers B/x latency
    if (gi + 1 < kcount)
      stage_dispatch(wave, xr, &ldsA[cur ^ 1][lane * ROW_S]);

    // (3) MFMA(g) from ldsA[cur] and prefetched B
    const short* abuf = ldsA[cur];
#pragma unroll
    for (int ks = 0; ks < 6; ++ks) {
      bf16x8 af[4];
#pragma unroll
      for (int mf = 0; mf < 4; ++mf)
        af[mf] = *(const bf16x8*)(abuf + (mf * 16 + l16) * ROW_S + ks * 32 + quad * 8);
#pragma unroll
      for (int mf = 0; mf < 4; ++mf)
#pragma unroll
        for (int nf = 0; nf < 2; ++nf)
          acc[mf][nf] = __builtin_amdgcn_mfma_f32_16x16x32_bf16(af[mf], ball[ks][nf], acc[mf][nf], 0, 0, 0);
    }

    if (gi + 2 < kcount) {
#pragma unroll
      for (int c = 0; c < 8; ++c) xr[c] = xn[c];
    }
    cur ^= 1;
    __syncthreads();   // single barrier: buf[cur^1] staged AND buf[cur] reads done
  }

  // epilogue: plain stores. bias only from the z=0 slice.
#pragma unroll
  for (int nf = 0; nf < 2; nf++) {
    const int col = n0 + wave * 32 + nf * 16 + l16;
    const float bv = (khalf == 0) ? bias[col] : 0.0f;
#pragma unroll
    for (int mf = 0; mf < 4; mf++) {
#pragma unroll
      for (int r = 0; r < 4; r++) {
        unsigned p2 = pp + (unsigned)(mf * 16 + quad * 4 + r);
        dst[(size_t)bb * 802816u + (size_t)col * 3136u + p2] = acc[mf][nf][r] + bv;
      }
    }
  }
}

// out += part, float4-vectorized; 802,816 float4s = 3136 blocks x 256 threads
__global__ __launch_bounds__(256) void reduce_add(float4* __restrict__ out,
                                                  const float4* __restrict__ part) {
  int i = blockIdx.x * 256 + threadIdx.x;
  float4 a = out[i];
  float4 b = part[i];
  a.x += b.x; a.y += b.y; a.z += b.z; a.w += b.w;
  out[i] = a;
}

extern "C" void kernel_launch(void* const* d_in, const int* in_sizes, int n_in,
                              void* d_out, int out_size, void* d_ws, size_t ws_size,
                              hipStream_t stream) {
  (void)in_sizes; (void)n_in; (void)out_size;
  const float* inp  = (const float*)d_in[0];
  const float* w    = (const float*)d_in[1];
  const float* bias = (const float*)d_in[2];
  const int*   pm2  = (const int*)d_in[3];
  const int*   pcm  = (const int*)d_in[4];
  int*   kmapG = (int*)d_ws;                      // 768 B (+pad to 1024)
  short* wbf   = (short*)((char*)d_ws + 1024);    // 3,145,728 B
  float* part  = (float*)((char*)d_ws + 1024 + 3145728);  // 12,845,056 B (opt)

  const size_t need = 1024u + 3145728u + 12845056u;
  const int nz = (ws_size >= need) ? 2 : 1;       // fallback = r14 behavior
  const int kcount = 32 / nz;

  build_kmap<<<1, 256, 0, stream>>>(pm2, pcm, kmapG);
  prep_w<<<768, 256, 0, stream>>>(w, kmapG, wbf);
  poly_gemm<<<dim3(196, 2, nz), 256, 0, stream>>>(inp, wbf, bias, (float*)d_out, part, kcount);
  if (nz == 2)
    reduce_add<<<3136, 256, 0, stream>>>((float4*)d_out, (const float4*)part);
}